// Round 2
// baseline (64.730 us; speedup 1.0000x reference)
//
#include <hip/hip_runtime.h>
#include <hip/hip_bf16.h>

#define MULC 128
#define IN_DIM 1152
#define ROWS_PER_WG 64
#define NTHREADS 256
#define W1T_PITCH 136   // ushorts; 272 B row stride -> b128 reads at structural-min banking

typedef __attribute__((ext_vector_type(8))) short bf16x8;
typedef __attribute__((ext_vector_type(4))) float f32x4;
typedef __attribute__((ext_vector_type(4))) unsigned short u16x4;

__device__ __forceinline__ unsigned short f2bf(float f) {
    unsigned int b = __builtin_bit_cast(unsigned int, f);
    b += 0x7fffu + ((b >> 16) & 1u);   // round-to-nearest-even
    return (unsigned short)(b >> 16);
}

// load one 96 B chunk (6 float4) for this lane
#define LOADC(r0,r1,r2,r3,r4,r5, kc) {                                  \
    const float4* p_ = (const float4*)(xbase + 96 * (kc));              \
    r0 = p_[0]; r1 = p_[1]; r2 = p_[2]; r3 = p_[3]; r4 = p_[4]; r5 = p_[5]; }

// deinterleave 24 floats (u-major, c-minor stride 3) into 3 bf16x8 A-fragments
#define FRAGS(F0,F1,F2, r0,r1,r2,r3,r4,r5)                                         \
    bf16x8 F0 = { (short)f2bf(r0.x), (short)f2bf(r0.w), (short)f2bf(r1.z),         \
                  (short)f2bf(r2.y), (short)f2bf(r3.x), (short)f2bf(r3.w),         \
                  (short)f2bf(r4.z), (short)f2bf(r5.y) };                          \
    bf16x8 F1 = { (short)f2bf(r0.y), (short)f2bf(r1.x), (short)f2bf(r1.w),         \
                  (short)f2bf(r2.z), (short)f2bf(r3.y), (short)f2bf(r4.x),         \
                  (short)f2bf(r4.w), (short)f2bf(r5.z) };                          \
    bf16x8 F2 = { (short)f2bf(r0.z), (short)f2bf(r1.y), (short)f2bf(r2.x),         \
                  (short)f2bf(r2.w), (short)f2bf(r3.z), (short)f2bf(r4.y),         \
                  (short)f2bf(r5.x), (short)f2bf(r5.w) };

#define MFMA_STEP(kc, F0,F1,F2)                                                     \
    _Pragma("unroll")                                                               \
    for (int nt = 0; nt < 8; ++nt) {                                                \
        bf16x8 bfr = *(const bf16x8*)&lds[(nt * 16 + li) * W1T_PITCH + (kc) * 32 + g * 8]; \
        acc[0][nt] = __builtin_amdgcn_mfma_f32_16x16x32_bf16(F0, bfr, acc[0][nt], 0, 0, 0); \
        acc[1][nt] = __builtin_amdgcn_mfma_f32_16x16x32_bf16(F1, bfr, acc[1][nt], 0, 0, 0); \
        acc[2][nt] = __builtin_amdgcn_mfma_f32_16x16x32_bf16(F2, bfr, acc[2][nt], 0, 0, 0); \
    }

__global__ __launch_bounds__(NTHREADS, 2)
void nltp_kernel(const float* __restrict__ x, const float* __restrict__ W1,
                 const float* __restrict__ W2, const float* __restrict__ tpw,
                 float* __restrict__ out)
{
    __shared__ __align__(16) unsigned short lds[128 * W1T_PITCH];  // W1^T only, 34.8 KB
    const int t  = threadIdx.x;
    const int n0 = blockIdx.x * ROWS_PER_WG;
    const int l  = t & 63;
    const int w  = t >> 6;      // wave 0..3 owns rows [16w, 16w+16)
    const int g  = l >> 4;      // k-group 0..3
    const int li = l & 15;      // row-in-tile

    const float* xbase = x + (size_t)(n0 + 16 * w + li) * IN_DIM + MULC + 24 * g;

    float4 a0,a1,a2,a3,a4,a5, b0,b1,b2,b3,b4,b5;
    LOADC(a0,a1,a2,a3,a4,a5, 0);          // chunk 0 in flight during W1 staging

    // ---- stage W1^T as bf16 (once) ----
    for (int it = 0; it < 16; ++it) {
        int tau = it * 256 + t;
        int v   = tau & 127;
        int u   = (tau >> 7) * 4;
        float f0 = W1[(u + 0) * MULC + v];
        float f1 = W1[(u + 1) * MULC + v];
        float f2 = W1[(u + 2) * MULC + v];
        float f3 = W1[(u + 3) * MULC + v];
        u16x4 pk = { f2bf(f0), f2bf(f1), f2bf(f2), f2bf(f3) };
        *(u16x4*)&lds[v * W1T_PITCH + u] = pk;
    }
    __syncthreads();   // the ONLY barrier

    f32x4 acc[3][8];
#pragma unroll
    for (int c = 0; c < 3; ++c)
#pragma unroll
        for (int nt = 0; nt < 8; ++nt)
            acc[c][nt] = (f32x4){0.f, 0.f, 0.f, 0.f};

    // ---- barrier-free K loop, register double-buffered ----
    LOADC(b0,b1,b2,b3,b4,b5, 1);
    { FRAGS(fa0,fa1,fa2, a0,a1,a2,a3,a4,a5); MFMA_STEP(0, fa0,fa1,fa2); }
    LOADC(a0,a1,a2,a3,a4,a5, 2);
    { FRAGS(fb0,fb1,fb2, b0,b1,b2,b3,b4,b5); MFMA_STEP(1, fb0,fb1,fb2); }
    LOADC(b0,b1,b2,b3,b4,b5, 3);
    { FRAGS(fc0,fc1,fc2, a0,a1,a2,a3,a4,a5); MFMA_STEP(2, fc0,fc1,fc2); }
    { FRAGS(fd0,fd1,fd2, b0,b1,b2,b3,b4,b5); MFMA_STEP(3, fd0,fd1,fd2); }

    // ---- epilogue: silu + W2 contraction + 16-lane reduce + TP readout ----
    const float inv = 0.08838834764831845f;  // 1/sqrt(128)
    float w2a[8], w2b[8];
#pragma unroll
    for (int nt = 0; nt < 8; ++nt) {
        float2 p = *(const float2*)(W2 + 2 * (nt * 16 + li));
        w2a[nt] = p.x; w2b[nt] = p.y;
    }
    float pa[3][4], pb[3][4];
#pragma unroll
    for (int c = 0; c < 3; ++c)
#pragma unroll
        for (int rg = 0; rg < 4; ++rg) { pa[c][rg] = 0.f; pb[c][rg] = 0.f; }

#pragma unroll
    for (int c = 0; c < 3; ++c)
#pragma unroll
        for (int nt = 0; nt < 8; ++nt)
#pragma unroll
            for (int rg = 0; rg < 4; ++rg) {
                float y = acc[c][nt][rg] * inv;
                float s = y / (1.f + __expf(-y));   // silu
                pa[c][rg] += s * w2a[nt];
                pb[c][rg] += s * w2b[nt];
            }

#pragma unroll
    for (int c = 0; c < 3; ++c)
#pragma unroll
        for (int rg = 0; rg < 4; ++rg) {
            float va = pa[c][rg], vb = pb[c][rg];
            va += __shfl_xor(va, 1, 16); vb += __shfl_xor(vb, 1, 16);
            va += __shfl_xor(va, 2, 16); vb += __shfl_xor(vb, 2, 16);
            va += __shfl_xor(va, 4, 16); vb += __shfl_xor(vb, 4, 16);
            va += __shfl_xor(va, 8, 16); vb += __shfl_xor(vb, 8, 16);
            pa[c][rg] = va * inv;
            pb[c][rg] = vb * inv;
        }

    const float tw0 = tpw[0], tw1 = tpw[1], tw2 = tpw[2];
    const float k0 = tw0 * 0.5773502691896258f;   // 1/sqrt(3)
    const float k1 = tw1 * 0.7071067811865476f;   // sqrt(3)/sqrt(6)
    const float s2 = 0.7071067811865476f;
    const float s6 = 0.4082482904638631f;         // 1/sqrt(6)

#pragma unroll
    for (int rg = 0; rg < 4; ++rg) {
        float a_0 = pa[0][rg], a_1 = pa[1][rg], a_2 = pa[2][rg];
        float b_0 = pb[0][rg], b_1 = pb[1][rg], b_2 = pb[2][rg];
        float o0 = k0 * (a_0 * b_0 + a_1 * b_1 + a_2 * b_2);
        float o1 = k1 * (a_1 * b_2 - a_2 * b_1);
        float o2 = k1 * (a_2 * b_0 - a_0 * b_2);
        float o3 = k1 * (a_0 * b_1 - a_1 * b_0);
        float o4 = tw2 * (s2 * (a_2 * b_0 + a_0 * b_2));
        float o5 = tw2 * (s2 * (a_0 * b_1 + a_1 * b_0));
        float o6 = tw2 * (s6 * (2.f * a_1 * b_1 - a_2 * b_2 - a_0 * b_0));
        float o7 = tw2 * (s2 * (a_2 * b_1 + a_1 * b_2));
        float o8 = tw2 * (s2 * (a_2 * b_2 - a_0 * b_0));
        float o = li == 0 ? o0 : li == 1 ? o1 : li == 2 ? o2 : li == 3 ? o3 :
                  li == 4 ? o4 : li == 5 ? o5 : li == 6 ? o6 : li == 7 ? o7 : o8;
        if (li < 9) {
            int row = n0 + 16 * w + 4 * g + rg;
            out[row * 9 + li] = o;
        }
    }
}

extern "C" void kernel_launch(void* const* d_in, const int* in_sizes, int n_in,
                              void* d_out, int out_size, void* d_ws, size_t ws_size,
                              hipStream_t stream) {
    const float* x   = (const float*)d_in[0];
    const float* W1  = (const float*)d_in[1];
    const float* W2  = (const float*)d_in[2];
    const float* tpw = (const float*)d_in[3];
    float* out = (float*)d_out;
    const int n = in_sizes[0] / IN_DIM;           // 131072
    dim3 grid(n / ROWS_PER_WG);                   // 2048
    nltp_kernel<<<grid, NTHREADS, 0, stream>>>(x, W1, W2, tpw, out);
}